// Round 9
// baseline (832.526 us; speedup 1.0000x reference)
//
#include <hip/hip_runtime.h>
#include <stdint.h>

#define B_  256
#define M_  80
#define T_  1000
#define H_  128
#define G3  384
#define KX  96    // fallback kernel x-K pad

typedef _Float16 half2_t __attribute__((ext_vector_type(2)));
typedef _Float16 half8  __attribute__((ext_vector_type(8)));
typedef float    f32x4  __attribute__((ext_vector_type(4)));

#define LOG2E 1.44269504f
#define MFMA(A, Bf, C) __builtin_amdgcn_mfma_f32_16x16x32_f16((A), (Bf), (C), 0, 0, 0)

__device__ __forceinline__ float fast_sigmoid(float v) {
    return __builtin_amdgcn_rcpf(1.0f + __builtin_amdgcn_exp2f(-LOG2E * v));
}
__device__ __forceinline__ float fast_tanh(float v) {
    return fmaf(-2.0f, __builtin_amdgcn_rcpf(1.0f + __builtin_amdgcn_exp2f(2.0f * LOG2E * v)), 1.0f);
}

// barrier that waits only on LDS ops — leaves global (gx) loads in flight
__device__ __forceinline__ void wg_barrier_lds() {
    asm volatile("s_waitcnt lgkmcnt(0)\n\ts_barrier" ::: "memory");
}

// ============================================================================
// Pre-pass: gx[b][g][t] = (x^T W_ih^T)[t][g] + b_ih[g] + (g<256 ? b_hh[g] : 0)
// f16, t-major rows (stride T_) -> rec reads are L1-line-amortized (32 t/line)
// and prepass stores are vector dwordx2 (4 consecutive t per lane).
// Grid (16 t-tiles, 256 b), 256 thr = 4 waves. x tile staged via LDS.
// ============================================================================
__global__ __launch_bounds__(256) void gx_gemm(
    const float* __restrict__ x, const float* __restrict__ W_ih,
    const float* __restrict__ b_ih, const float* __restrict__ b_hh,
    uint16_t* __restrict__ gx)
{
    const int b  = blockIdx.y;
    const int t0 = blockIdx.x * 64;
    const int tid = threadIdx.x;
    const int l = tid & 63, w = tid >> 6;
    const int jn = l & 15, kq = l >> 4;

    __shared__ _Float16 xl[64][104];   // [t][k], k padded 80->104 (2-way banks)

    // stage x tile (coalesced in t), zero k-pad
    const float* xb = x + (size_t)b * M_ * T_;
#pragma unroll
    for (int it = 0; it < 26; ++it) {            // 64*104/256 = 26
        const int idx = tid + 256 * it;
        const int t = idx & 63, k = idx >> 6;    // k 0..103
        int tg = t0 + t; if (tg >= T_) tg = T_ - 1;
        const float v = (k < M_) ? xb[(size_t)k * T_ + tg] : 0.0f;
        xl[t][k] = (_Float16)v;
    }

    // B-frags (W_ih) + fused bias
    half8 bf[6][3];
    float bias[6];
#pragma unroll
    for (int nt = 0; nt < 6; ++nt) {
        const int g = 16 * (6 * w + nt) + jn;
        bias[nt] = b_ih[g] + (g < 2 * H_ ? b_hh[g] : 0.0f);
        const float* wp = W_ih + g * M_;
#pragma unroll
        for (int f = 0; f < 3; ++f)
#pragma unroll
            for (int j = 0; j < 8; ++j) {
                const int k = 32 * f + 8 * kq + j;
                bf[nt][f][j] = (k < M_) ? (_Float16)wp[k] : (_Float16)0.0f;
            }
    }
    __syncthreads();

    uint16_t* gb = gx + (size_t)b * G3 * T_;

#pragma unroll
    for (int mt = 0; mt < 4; ++mt) {
        half8 af[3];
#pragma unroll
        for (int f = 0; f < 3; ++f)
            af[f] = *(const half8*)&xl[16 * mt + jn][32 * f + 8 * kq];

        const int trow = t0 + 16 * mt + 4 * kq;   // D rows: trow + reg (t)
#pragma unroll
        for (int nt = 0; nt < 6; ++nt) {
            f32x4 acc = { bias[nt], bias[nt], bias[nt], bias[nt] };
            acc = MFMA(af[0], bf[nt][0], acc);
            acc = MFMA(af[1], bf[nt][1], acc);
            acc = MFMA(af[2], bf[nt][2], acc);
            const int g = 16 * (6 * w + nt) + jn;
            if (trow < T_) {                      // trow%4==0, T_%4==0 -> no straddle
                half2_t lo; lo.x = (_Float16)acc[0]; lo.y = (_Float16)acc[1];
                half2_t hi; hi.x = (_Float16)acc[2]; hi.y = (_Float16)acc[3];
                uint2 pk = { __builtin_bit_cast(uint32_t, lo),
                             __builtin_bit_cast(uint32_t, hi) };
                *(uint2*)(gb + (size_t)g * T_ + trow) = pk;
            }
        }
    }
}

// ============================================================================
// Recurrence: h-side MFMA only. gx[b][g][t] streamed with distance-2 prefetch
// (scalar ushort loads, L1-amortized lines). LDS-only barrier per step keeps
// gx loads in flight. Zero-init MFMA C; gx folded in at gate time.
// ============================================================================
__global__ __launch_bounds__(512, 2) void gru_rec(
    const uint16_t* __restrict__ gx, const float* __restrict__ W_hh,
    const float* __restrict__ b_hh, float* __restrict__ out)
{
    const int b = blockIdx.x;
    const int tid = threadIdx.x;
    const int l = tid & 63, w = tid >> 6;
    const int jn = l & 15, kq = l >> 4;
    const int hid = 16 * w + jn;

    __shared__ __align__(16) _Float16 h16[2][H_];

    half8 wr[4], wz[4], wn[4];
#pragma unroll
    for (int f = 0; f < 4; ++f)
#pragma unroll
        for (int j = 0; j < 8; ++j) {
            const int k = 32 * f + 8 * kq + j;
            wr[f][j] = (_Float16)W_hh[(hid)          * H_ + k];
            wz[f][j] = (_Float16)W_hh[(H_ + hid)     * H_ + k];
            wn[f][j] = (_Float16)W_hh[(2 * H_ + hid) * H_ + k];
        }
#pragma unroll
    for (int f = 0; f < 4; ++f) {
        asm volatile("" : "+v"(wr[f]));
        asm volatile("" : "+v"(wz[f]));
        asm volatile("" : "+v"(wn[f]));
    }

    const float bN = b_hh[2 * H_ + hid];
    const uint16_t* pR = gx + ((size_t)b * G3 + hid) * T_;
    const uint16_t* pZ = pR + (size_t)H_ * T_;
    const uint16_t* pN = pR + (size_t)(2 * H_) * T_;

    if (tid < H_) h16[0][tid] = (_Float16)0.0f;

    uint16_t ra = pR[0], za = pZ[0], na = pN[0];
    uint16_t rb = pR[1], zb = pZ[1], nb2 = pN[1];

    const f32x4 zero4 = { 0.f, 0.f, 0.f, 0.f };
    float h_r = 0.0f;

    for (int t = 0; t < T_; t += 2) {
        // ---- even step: reads h16[0], writes h16[1]; prefetch t+2 ----
        wg_barrier_lds();
        const int i2 = (t + 2 < T_) ? t + 2 : T_ - 1;     // scalar clamp
        const uint16_t rc = pR[i2], zc = pZ[i2], nc = pN[i2];
        {
            const int ko = 8 * kq;
            const half8 ah0 = *(const half8*)&h16[0][ko];
            const half8 ah1 = *(const half8*)&h16[0][32 + ko];
            const half8 ah2 = *(const half8*)&h16[0][64 + ko];
            const half8 ah3 = *(const half8*)&h16[0][96 + ko];
            f32x4 aR = MFMA(ah0, wr[0], zero4);
            f32x4 aZ = MFMA(ah0, wz[0], zero4);
            f32x4 aN = MFMA(ah0, wn[0], zero4);
            aR = MFMA(ah1, wr[1], aR); aZ = MFMA(ah1, wz[1], aZ); aN = MFMA(ah1, wn[1], aN);
            aR = MFMA(ah2, wr[2], aR); aZ = MFMA(ah2, wz[2], aZ); aN = MFMA(ah2, wn[2], aN);
            aR = MFMA(ah3, wr[3], aR); aZ = MFMA(ah3, wz[3], aZ); aN = MFMA(ah3, wn[3], aN);
            const float r  = fast_sigmoid(aR[0] + (float)__builtin_bit_cast(_Float16, ra));
            const float z  = fast_sigmoid(aZ[0] + (float)__builtin_bit_cast(_Float16, za));
            const float nv = fast_tanh(fmaf(r, aN[0] + bN,
                                            (float)__builtin_bit_cast(_Float16, na)));
            h_r = fmaf(z, h_r - nv, nv);
            if (l < 16) h16[1][hid] = (_Float16)h_r;
        }
        // ---- odd step: reads h16[1], writes h16[0]; prefetch t+3 ----
        wg_barrier_lds();
        const int i3 = (t + 3 < T_) ? t + 3 : T_ - 1;
        const uint16_t rd = pR[i3], zd = pZ[i3], nd = pN[i3];
        {
            const int ko = 8 * kq;
            const half8 ah0 = *(const half8*)&h16[1][ko];
            const half8 ah1 = *(const half8*)&h16[1][32 + ko];
            const half8 ah2 = *(const half8*)&h16[1][64 + ko];
            const half8 ah3 = *(const half8*)&h16[1][96 + ko];
            f32x4 aR = MFMA(ah0, wr[0], zero4);
            f32x4 aZ = MFMA(ah0, wz[0], zero4);
            f32x4 aN = MFMA(ah0, wn[0], zero4);
            aR = MFMA(ah1, wr[1], aR); aZ = MFMA(ah1, wz[1], aZ); aN = MFMA(ah1, wn[1], aN);
            aR = MFMA(ah2, wr[2], aR); aZ = MFMA(ah2, wz[2], aZ); aN = MFMA(ah2, wn[2], aN);
            aR = MFMA(ah3, wr[3], aR); aZ = MFMA(ah3, wz[3], aZ); aN = MFMA(ah3, wn[3], aN);
            const float r  = fast_sigmoid(aR[0] + (float)__builtin_bit_cast(_Float16, rb));
            const float z  = fast_sigmoid(aZ[0] + (float)__builtin_bit_cast(_Float16, zb));
            const float nv = fast_tanh(fmaf(r, aN[0] + bN,
                                            (float)__builtin_bit_cast(_Float16, nb2)));
            h_r = fmaf(z, h_r - nv, nv);
            if (l < 16) h16[0][hid] = (_Float16)h_r;
        }
        ra = rc; za = zc; na = nc;
        rb = rd; zb = zd; nb2 = nd;
    }

    if (l < 16) out[(size_t)b * H_ + hid] = h_r;
}

// ============================================================================
// Fallback (R7 structure, verified 656 us) if ws can't hold gx.
// ============================================================================
__device__ __forceinline__ float wget(const float* __restrict__ W_ih,
                                      const float* __restrict__ W_hh,
                                      int row, int k) {
    if (k < H_) return W_hh[row * H_ + k];
    const int c = k - H_;
    return (c < M_) ? W_ih[row * M_ + c] : 0.0f;
}

__global__ __launch_bounds__(512, 2) void gru_fused(
    const float* __restrict__ x, const float* __restrict__ W_ih,
    const float* __restrict__ W_hh, const float* __restrict__ b_ih,
    const float* __restrict__ b_hh, float* __restrict__ out)
{
    const int b   = blockIdx.x;
    const int tid = threadIdx.x;
    const int l   = tid & 63;
    const int w   = tid >> 6;
    const int jn  = l & 15;
    const int kq  = l >> 4;
    const int hid = w * 16 + jn;

    __shared__ __align__(16) _Float16 h16[2][H_];
    __shared__ __align__(16) _Float16 xs[2][KX];

    half8 wr[7], wz[7], wnh[4], wnx[3];
#pragma unroll
    for (int f = 0; f < 7; ++f)
#pragma unroll
        for (int j = 0; j < 8; ++j) {
            const int k = 32 * f + kq * 8 + j;
            wr[f][j] = (_Float16)wget(W_ih, W_hh, hid,      k);
            wz[f][j] = (_Float16)wget(W_ih, W_hh, H_ + hid, k);
        }
#pragma unroll
    for (int f = 0; f < 4; ++f)
#pragma unroll
        for (int j = 0; j < 8; ++j)
            wnh[f][j] = (_Float16)wget(W_ih, W_hh, 2 * H_ + hid, 32 * f + kq * 8 + j);
#pragma unroll
    for (int f = 0; f < 3; ++f)
#pragma unroll
        for (int j = 0; j < 8; ++j)
            wnx[f][j] = (_Float16)wget(W_ih, W_hh, 2 * H_ + hid, H_ + 32 * f + kq * 8 + j);
#pragma unroll
    for (int f = 0; f < 7; ++f) { asm volatile("" : "+v"(wr[f])); asm volatile("" : "+v"(wz[f])); }
#pragma unroll
    for (int f = 0; f < 4; ++f) asm volatile("" : "+v"(wnh[f]));
#pragma unroll
    for (int f = 0; f < 3; ++f) asm volatile("" : "+v"(wnx[f]));

    const float bR  = b_ih[hid] + b_hh[hid];
    const float bZ  = b_ih[H_ + hid] + b_hh[H_ + hid];
    const float bNX = b_ih[2 * H_ + hid];
    const float bNH = b_hh[2 * H_ + hid];

    const float* xb  = x + (size_t)b * M_ * T_;
    const int    toff = tid * T_;

    if (tid < H_) h16[0][tid] = (_Float16)0.0f;
    if (tid < 2 * KX) ((short*)xs)[tid] = 0;
    if (tid < M_) xs[0][tid] = (_Float16)xb[toff];

    float h_r = 0.0f;

    for (int t = 0; t < T_; ++t) {
        __syncthreads();
        const int cb = t & 1, nb = cb ^ 1;

        float xv = 0.0f;
        const int tn = (t + 1 < T_) ? (t + 1) : (T_ - 1);
        const float* xc = xb + tn;
        if (tid < M_) xv = xc[toff];

        const int ko = kq * 8;
        const half8 ah0 = *(const half8*)&h16[cb][ko];
        const half8 ah1 = *(const half8*)&h16[cb][32 + ko];
        const half8 ah2 = *(const half8*)&h16[cb][64 + ko];
        const half8 ah3 = *(const half8*)&h16[cb][96 + ko];
        const half8 ax0 = *(const half8*)&xs[cb][ko];
        const half8 ax1 = *(const half8*)&xs[cb][32 + ko];
        const half8 ax2 = *(const half8*)&xs[cb][64 + ko];

        f32x4 aR  = { bR,  bR,  bR,  bR  };
        f32x4 aZ  = { bZ,  bZ,  bZ,  bZ  };
        f32x4 aNX = { bNX, bNX, bNX, bNX };
        f32x4 aNH = { bNH, bNH, bNH, bNH };

        aR  = MFMA(ah0, wr[0],  aR);
        aZ  = MFMA(ah0, wz[0],  aZ);
        aNH = MFMA(ah0, wnh[0], aNH);
        aR  = MFMA(ah1, wr[1],  aR);
        aZ  = MFMA(ah1, wz[1],  aZ);
        aNH = MFMA(ah1, wnh[1], aNH);
        aR  = MFMA(ah2, wr[2],  aR);
        aZ  = MFMA(ah2, wz[2],  aZ);
        aNH = MFMA(ah2, wnh[2], aNH);
        aR  = MFMA(ah3, wr[3],  aR);
        aZ  = MFMA(ah3, wz[3],  aZ);
        aNH = MFMA(ah3, wnh[3], aNH);
        aR  = MFMA(ax0, wr[4],  aR);
        aZ  = MFMA(ax0, wz[4],  aZ);
        aNX = MFMA(ax0, wnx[0], aNX);
        aR  = MFMA(ax1, wr[5],  aR);
        aZ  = MFMA(ax1, wz[5],  aZ);
        aNX = MFMA(ax1, wnx[1], aNX);
        aR  = MFMA(ax2, wr[6],  aR);
        aZ  = MFMA(ax2, wz[6],  aZ);
        aNX = MFMA(ax2, wnx[2], aNX);

        if (tid < M_) xs[nb][tid] = (_Float16)xv;

        const float r  = fast_sigmoid(aR[0]);
        const float z  = fast_sigmoid(aZ[0]);
        const float nv = fast_tanh(fmaf(r, aNH[0], aNX[0]));
        h_r = fmaf(z, h_r - nv, nv);
        if (l < 16) h16[nb][hid] = (_Float16)h_r;
    }

    if (l < 16) out[(size_t)b * H_ + hid] = h_r;
}

extern "C" void kernel_launch(void* const* d_in, const int* in_sizes, int n_in,
                              void* d_out, int out_size, void* d_ws, size_t ws_size,
                              hipStream_t stream) {
    const float* x    = (const float*)d_in[0];
    const float* W_ih = (const float*)d_in[1];
    const float* W_hh = (const float*)d_in[2];
    const float* b_ih = (const float*)d_in[3];
    const float* b_hh = (const float*)d_in[4];
    float* out = (float*)d_out;

    const size_t gx_bytes = (size_t)B_ * G3 * T_ * sizeof(uint16_t);
    if (ws_size >= gx_bytes) {
        uint16_t* gx = (uint16_t*)d_ws;
        gx_gemm<<<dim3(16, B_), dim3(256), 0, stream>>>(x, W_ih, b_ih, b_hh, gx);
        gru_rec<<<dim3(B_), dim3(512), 0, stream>>>(gx, W_hh, b_hh, out);
    } else {
        gru_fused<<<dim3(B_), dim3(512), 0, stream>>>(x, W_ih, W_hh, b_ih, b_hh, out);
    }
}

// Round 10
// 444.621 us; speedup vs baseline: 1.8724x; 1.8724x over previous
//
#include <hip/hip_runtime.h>
#include <stdint.h>

#define B_   256
#define M_   80
#define T_   1000
#define H_   128
#define G3   384
#define TILE 32
#define NT_  32          // ceil(1000/32); last tile has 8 steps
#define XPAD 104         // x-tile row pad (mel 80 -> 104)
#define GPAD 388         // gxt row pad: 776 B -> 4*rowstride = 8 banks offset/kq row

typedef _Float16 half8 __attribute__((ext_vector_type(8)));
typedef float    f32x4 __attribute__((ext_vector_type(4)));

#define LOG2E 1.44269504f
#define MFMA(A, Bf, C) __builtin_amdgcn_mfma_f32_16x16x32_f16((A), (Bf), (C), 0, 0, 0)

__device__ __forceinline__ float fast_sigmoid(float v) {
    return __builtin_amdgcn_rcpf(1.0f + __builtin_amdgcn_exp2f(-LOG2E * v));
}
__device__ __forceinline__ float fast_tanh(float v) {
    return fmaf(-2.0f, __builtin_amdgcn_rcpf(1.0f + __builtin_amdgcn_exp2f(2.0f * LOG2E * v)), 1.0f);
}

// One block per batch element (grid 256 = CU count), 512 thr = 8 waves (2/SIMD).
// Super-iteration: phase A computes gxt[t][g] = x_t.W_ih^T + bias for 32 t via
// DENSE-M MFMA (t = M dim, 18 MFMA/wave per 32 steps ~ 22 cyc/step), then 32
// recurrence steps (12 h-MFMA/wave, M-broadcast) read gates from gxt in LDS.
// Inner loop is LDS-only: no global loads, cheap __syncthreads. h double-buffered.
__global__ __launch_bounds__(512, 2) void gru_tile(
    const float* __restrict__ x,      // (B, M, T)
    const float* __restrict__ W_ih,   // (3H, M)
    const float* __restrict__ W_hh,   // (3H, H)
    const float* __restrict__ b_ih,   // (3H,)
    const float* __restrict__ b_hh,   // (3H,)
    float* __restrict__ out)          // (B, H)
{
    const int b   = blockIdx.x;
    const int tid = threadIdx.x;
    const int l   = tid & 63;
    const int w   = tid >> 6;      // wave 0..7
    const int jn  = l & 15;        // MFMA n / m row within tile
    const int kq  = l >> 4;        // quad: k-base 8*kq
    const int hid = 16 * w + jn;   // hidden unit owned (recurrence N)

    __shared__ __align__(16) _Float16 gxt[TILE][GPAD];      // gate inputs for tile
    __shared__ __align__(16) _Float16 xt16[2][TILE][XPAD];  // x tiles [t][mel], dbuf
    __shared__ __align__(16) _Float16 h16[2][H_];           // h state, dbuf

    // ---- W_hh B-frags (recurrence): wr/wz/wn[f][j] = W_hh[row][32f+8kq+j] ----
    half8 wr[4], wz[4], wn[4];
#pragma unroll
    for (int f = 0; f < 4; ++f)
#pragma unroll
        for (int j = 0; j < 8; ++j) {
            const int k = 32 * f + 8 * kq + j;
            wr[f][j] = (_Float16)W_hh[(hid)          * H_ + k];
            wz[f][j] = (_Float16)W_hh[(H_ + hid)     * H_ + k];
            wn[f][j] = (_Float16)W_hh[(2 * H_ + hid) * H_ + k];
        }
#pragma unroll
    for (int f = 0; f < 4; ++f) {
        asm volatile("" : "+v"(wr[f]));
        asm volatile("" : "+v"(wz[f]));
        asm volatile("" : "+v"(wn[f]));
    }

    // ---- W_ih B-frags (phase A): wave w owns gate-rows nt = 3w+i ----
    half8 wih[3][3];
    float biasA[3];
#pragma unroll
    for (int i = 0; i < 3; ++i) {
        const int g = 16 * (3 * w + i) + jn;
        biasA[i] = b_ih[g] + (g < 2 * H_ ? b_hh[g] : 0.0f);
        const float* wp = W_ih + g * M_;
#pragma unroll
        for (int f = 0; f < 3; ++f)
#pragma unroll
            for (int j = 0; j < 8; ++j) {
                const int k = 32 * f + 8 * kq + j;
                wih[i][f][j] = (k < M_) ? (_Float16)wp[k] : (_Float16)0.0f;
            }
    }
#pragma unroll
    for (int i = 0; i < 3; ++i) {
        asm volatile("" : "+v"(wih[i][0]));
        asm volatile("" : "+v"(wih[i][1]));
        asm volatile("" : "+v"(wih[i][2]));
    }
    asm volatile("" : "+v"(biasA[0]), "+v"(biasA[1]), "+v"(biasA[2]));

    const float bN = b_hh[2 * H_ + hid];
    const float* xb = x + (size_t)b * M_ * T_;

    // ---- init: zero x-tile pads + h0, then stage x tile 0 ----
    for (int i = tid; i < 2 * TILE * XPAD; i += 512) ((short*)xt16)[i] = 0;
    if (tid < H_) h16[0][tid] = (_Float16)0.0f;
    __syncthreads();
    {
        const int tq = tid & 7, m0 = tid >> 3;     // 64 mels x 8 quads
        float4 v0 = *(const float4*)&xb[(size_t)m0 * T_ + 4 * tq];
#pragma unroll
        for (int e = 0; e < 4; ++e) xt16[0][4 * tq + e][m0] = (_Float16)v0[e];
        if (tid < 128) {
            float4 v1 = *(const float4*)&xb[(size_t)(64 + m0) * T_ + 4 * tq];
#pragma unroll
            for (int e = 0; e < 4; ++e) xt16[0][4 * tq + e][64 + m0] = (_Float16)v1[e];
        }
    }
    __syncthreads();

    const f32x4 zero4 = { 0.f, 0.f, 0.f, 0.f };
    float h_r = 0.0f;

    for (int tb = 0; tb < NT_; ++tb) {
        // ================= phase A =================
        // prefetch next x tile (t1 multiple of 4; T_ multiple of 4 -> no straddle)
        const int t1 = TILE * (tb + 1);
        const int tq = tid & 7, m0 = tid >> 3;
        float4 xv0, xv1;
        const bool doPref = (t1 < T_);
        if (doPref) {
            const int tc0 = t1 + 4 * tq;
            const int tc  = (tc0 <= T_ - 4) ? tc0 : (T_ - 4);  // clamped slots unused
            xv0 = *(const float4*)&xb[(size_t)m0 * T_ + tc];
            if (tid < 128) xv1 = *(const float4*)&xb[(size_t)(64 + m0) * T_ + tc];
        }
        // gxt = x_tile . W_ih^T + bias (dense-M MFMA; M = t)
        const int cbuf = tb & 1, nbuf = cbuf ^ 1;
#pragma unroll
        for (int mt = 0; mt < 2; ++mt) {
            half8 af[3];
#pragma unroll
            for (int f = 0; f < 3; ++f)
                af[f] = *(const half8*)&xt16[cbuf][16 * mt + jn][32 * f + 8 * kq];
#pragma unroll
            for (int i = 0; i < 3; ++i) {
                f32x4 acc = { biasA[i], biasA[i], biasA[i], biasA[i] };
                acc = MFMA(af[0], wih[i][0], acc);
                acc = MFMA(af[1], wih[i][1], acc);
                acc = MFMA(af[2], wih[i][2], acc);
                const int g    = 16 * (3 * w + i) + jn;
                const int trow = 16 * mt + 4 * kq;
#pragma unroll
                for (int r2 = 0; r2 < 4; ++r2)
                    gxt[trow + r2][g] = (_Float16)acc[r2];
            }
        }
        // publish prefetched x tile
        if (doPref) {
#pragma unroll
            for (int e = 0; e < 4; ++e) xt16[nbuf][4 * tq + e][m0] = (_Float16)xv0[e];
            if (tid < 128) {
#pragma unroll
                for (int e = 0; e < 4; ++e) xt16[nbuf][4 * tq + e][64 + m0] = (_Float16)xv1[e];
            }
        }
        __syncthreads();     // gxt + next x tile ready

        // ================= phase B: recurrence steps =================
        const int rem    = T_ - TILE * tb;
        const int nsteps = (rem < TILE) ? rem : TILE;   // 32 or 8 (both even)
        for (int tt = 0; tt < nsteps; tt += 2) {
            // ---- even step: reads h16[0], writes h16[1] ----
            {
                const int ko = 8 * kq;
                const half8 a0 = *(const half8*)&h16[0][ko];
                const half8 a1 = *(const half8*)&h16[0][32 + ko];
                const half8 a2 = *(const half8*)&h16[0][64 + ko];
                const half8 a3 = *(const half8*)&h16[0][96 + ko];
                const float gr = (float)gxt[tt][hid];
                const float gz = (float)gxt[tt][H_ + hid];
                const float gn = (float)gxt[tt][2 * H_ + hid];
                f32x4 aR = MFMA(a0, wr[0], zero4);
                f32x4 aZ = MFMA(a0, wz[0], zero4);
                f32x4 aN = MFMA(a0, wn[0], zero4);
                aR = MFMA(a1, wr[1], aR); aZ = MFMA(a1, wz[1], aZ); aN = MFMA(a1, wn[1], aN);
                aR = MFMA(a2, wr[2], aR); aZ = MFMA(a2, wz[2], aZ); aN = MFMA(a2, wn[2], aN);
                aR = MFMA(a3, wr[3], aR); aZ = MFMA(a3, wz[3], aZ); aN = MFMA(a3, wn[3], aN);
                const float r  = fast_sigmoid(aR[0] + gr);
                const float z  = fast_sigmoid(aZ[0] + gz);
                const float nv = fast_tanh(fmaf(r, aN[0] + bN, gn));
                h_r = fmaf(z, h_r - nv, nv);
                if (l < 16) h16[1][hid] = (_Float16)h_r;
            }
            __syncthreads();
            // ---- odd step: reads h16[1], writes h16[0] ----
            {
                const int ko = 8 * kq;
                const half8 a0 = *(const half8*)&h16[1][ko];
                const half8 a1 = *(const half8*)&h16[1][32 + ko];
                const half8 a2 = *(const half8*)&h16[1][64 + ko];
                const half8 a3 = *(const half8*)&h16[1][96 + ko];
                const float gr = (float)gxt[tt + 1][hid];
                const float gz = (float)gxt[tt + 1][H_ + hid];
                const float gn = (float)gxt[tt + 1][2 * H_ + hid];
                f32x4 aR = MFMA(a0, wr[0], zero4);
                f32x4 aZ = MFMA(a0, wz[0], zero4);
                f32x4 aN = MFMA(a0, wn[0], zero4);
                aR = MFMA(a1, wr[1], aR); aZ = MFMA(a1, wz[1], aZ); aN = MFMA(a1, wn[1], aN);
                aR = MFMA(a2, wr[2], aR); aZ = MFMA(a2, wz[2], aZ); aN = MFMA(a2, wn[2], aN);
                aR = MFMA(a3, wr[3], aR); aZ = MFMA(a3, wz[3], aZ); aN = MFMA(a3, wn[3], aN);
                const float r  = fast_sigmoid(aR[0] + gr);
                const float z  = fast_sigmoid(aZ[0] + gz);
                const float nv = fast_tanh(fmaf(r, aN[0] + bN, gn));
                h_r = fmaf(z, h_r - nv, nv);
                if (l < 16) h16[0][hid] = (_Float16)h_r;
            }
            __syncthreads();
        }
    }

    if (l < 16) out[(size_t)b * H_ + hid] = h_r;
}

extern "C" void kernel_launch(void* const* d_in, const int* in_sizes, int n_in,
                              void* d_out, int out_size, void* d_ws, size_t ws_size,
                              hipStream_t stream) {
    const float* x    = (const float*)d_in[0];
    const float* W_ih = (const float*)d_in[1];
    const float* W_hh = (const float*)d_in[2];
    const float* b_ih = (const float*)d_in[3];
    const float* b_hh = (const float*)d_in[4];
    float* out = (float*)d_out;

    gru_tile<<<dim3(B_), dim3(512), 0, stream>>>(x, W_ih, W_hh, b_ih, b_hh, out);
}